// Round 7
// baseline (194.054 us; speedup 1.0000x reference)
//
#include <hip/hip_runtime.h>
#include <hip/hip_bf16.h>

// EdgePredictor: out[e] = relu(concat(X[row], X[col]) @ W1 + b1) @ W2 + b2
// Precompute per-node AB[n][256] = {X[n]@W1[:128,:] | X[n]@W1[128:,:]} in f16.
// Per edge: out = relu(A[row] + B[col] + b1) @ W2 + b2.
//
// R16: R15 failed correctness; audit pins the risk on inline-asm operand
// binding (HIP int4 is a struct, not an ext_vector -> "=v" tuple binding
// undefined) and RA spills of asm in-flight load dests. Since R11=R13=R14
// proved asm pipelining buys nothing (request-count wall, not latency),
// edge_mlp is now PLAIN HIP over the sorted streams: compiler-inserted
// waits guarantee correctness; the sort's within-wave row duplication
// still merges A-side line requests in the coalescer (the actual lever).

#define EMBED 128

typedef _Float16 half8 __attribute__((ext_vector_type(8)));
typedef _Float16 half4 __attribute__((ext_vector_type(4)));
typedef float floatx4 __attribute__((ext_vector_type(4)));
typedef int intx4 __attribute__((ext_vector_type(4)));

// --- Kernel 0: fused prep (+ counter zeroing for the sort).
// Blocks 0..127: transpose+convert W1 -> WT. Block 128: flag/W2PT/b1f.
// Blocks 129..129+NB-1: zero cnt[NB*1024].
__global__ __launch_bounds__(256) void prep(
    const float* __restrict__ W1, const float* __restrict__ W2,
    const float* __restrict__ b1, const int* __restrict__ idx,
    _Float16* __restrict__ WT, _Float16* __restrict__ W2PT,
    _Float16* __restrict__ b1f, int* __restrict__ flag,
    int* __restrict__ cnt) {
    if (blockIdx.x < 128) {
        __shared__ float lds[16][17];
        const int ty = threadIdx.x >> 4, tx = threadIdx.x & 15;
        const int r0 = (blockIdx.x >> 3) * 16;   // source W1 row tile
        const int c0 = (blockIdx.x & 7) * 16;    // source W1 col tile
        lds[ty][tx] = W1[(r0 + ty) * 128 + c0 + tx];
        __syncthreads();
        const int jbase = c0 + (r0 >= 128 ? 128 : 0);
        const int kbase = r0 & 127;
        WT[(size_t)(jbase + ty) * 128 + kbase + tx] = (_Float16)lds[tx][ty];
    } else if (blockIdx.x == 128) {
        const int t = threadIdx.x;
        if (t < 64) {  // int64 layout iff first 64 high words are all zero
            const int hw = idx[2 * t + 1];
            const unsigned long long m = __ballot(hw != 0);
            if (t == 0) *flag = (m == 0ull) ? 1 : 0;
        }
        if (t < 128) b1f[t] = (_Float16)b1[t];
        for (int i = t; i < 2048; i += 256) {  // W2PT[n][k] = n<2 ? W2[k][n] : 0
            const int n = i >> 7, k = i & 127;
            W2PT[i] = (n < 2) ? (_Float16)W2[k * 2 + n] : (_Float16)0.f;
        }
    } else {  // zero 1024 counters per block (int4 stores)
        const int i = (blockIdx.x - 129) * 256 + threadIdx.x;
        ((intx4*)cnt)[i] = (intx4){0, 0, 0, 0};
    }
}

// --- Sort 1: histogram of row endpoints.
__global__ __launch_bounds__(256) void hist(
    const int* __restrict__ eidx, const int* __restrict__ flag,
    int* __restrict__ cnt, int n_edges) {
    const int mode = *flag;
    for (int e = blockIdx.x * 256 + threadIdx.x; e < n_edges;
         e += gridDim.x * 256) {
        const int r = eidx[(size_t)e << mode];
        atomicAdd(&cnt[r], 1);
    }
}

// --- Sort 2: per-1024-block exclusive scan (in place) + block totals.
__global__ __launch_bounds__(1024) void scan1(
    int* __restrict__ cnt, int* __restrict__ bsum, int nn) {
    __shared__ int wsums[16];
    const int t = threadIdx.x, lane = t & 63, w = t >> 6;
    const int i = blockIdx.x * 1024 + t;
    const int v = (i < nn) ? cnt[i] : 0;
    int x = v;  // wave inclusive scan
#pragma unroll
    for (int d = 1; d < 64; d <<= 1) {
        const int y = __shfl_up(x, d, 64);
        if (lane >= d) x += y;
    }
    if (lane == 63) wsums[w] = x;
    __syncthreads();
    if (w == 0 && lane < 16) {  // exclusive scan of 16 wave sums
        const int s = wsums[lane];
        int xs = s;
#pragma unroll
        for (int d = 1; d < 16; d <<= 1) {
            const int y = __shfl_up(xs, d, 64);
            if (lane >= d) xs += y;
        }
        wsums[lane] = xs - s;
    }
    __syncthreads();
    if (i < nn) cnt[i] = x - v + wsums[w];  // exclusive within block
    if (t == 1023) bsum[blockIdx.x] = x + wsums[15];  // block total
}

// --- Sort 3: exclusive scan of block totals (NB <= 128) + pad sorted tail.
__global__ __launch_bounds__(128) void scan2(
    int* __restrict__ bsum, int nb, int* __restrict__ sR,
    int* __restrict__ sC, int* __restrict__ sE, int n_edges, int g16) {
    __shared__ int wtot[2];
    const int t = threadIdx.x, lane = t & 63, w = t >> 6;
    const int v = (t < nb) ? bsum[t] : 0;
    int x = v;
#pragma unroll
    for (int d = 1; d < 64; d <<= 1) {
        const int y = __shfl_up(x, d, 64);
        if (lane >= d) x += y;
    }
    if (lane == 63) wtot[w] = x;
    __syncthreads();
    const int excl = x - v + (w == 1 ? wtot[0] : 0);
    if (t < nb) bsum[t] = excl;
    if (t < 16) {  // zero pad tail of sorted arrays (row 0 is safe to gather)
        const int p = n_edges + t;
        if (p < g16) { sR[p] = 0; sC[p] = 0; sE[p] = 0; }
    }
}

// --- Sort 4: scatter edges to sorted-by-row positions.
__global__ __launch_bounds__(256) void scatter(
    const int* __restrict__ eidx, const int* __restrict__ flag,
    int* __restrict__ pos, const int* __restrict__ boff,
    int* __restrict__ sR, int* __restrict__ sC, int* __restrict__ sE,
    int n_edges) {
    const int mode = *flag;
    for (int e = blockIdx.x * 256 + threadIdx.x; e < n_edges;
         e += gridDim.x * 256) {
        const int r = eidx[(size_t)e << mode];
        const int c = eidx[((size_t)n_edges + e) << mode];
        const int p = atomicAdd(&pos[r], 1) + boff[r >> 10];
        sR[p] = r; sC[p] = c; sE[p] = e;
    }
}

// --- Kernel 1: AB = [X | X] @ Wcat via f16 MFMA, operand-swapped
// (A-operand = W-frag so D rows are output cols). Grid-stride, 2 tiles per
// block; next tile's X loads prefetched into registers during compute.
__global__ __launch_bounds__(256) void gemm_ab(
    const float* __restrict__ X, const _Float16* __restrict__ WT,
    _Float16* __restrict__ AB, int n_nodes, int n_tiles) {
    __shared__ _Float16 sh[64 * 264];  // 33792 B union: xs(17408) / outs(33792)
    _Float16* xs   = sh;               // stride 136
    _Float16* outs = sh;               // stride 264
    const int t = threadIdx.x;
    const int w = t >> 6, lane = t & 63, lm = lane & 15, quad = lane >> 4;

    int srow[8], scol[8];
#pragma unroll
    for (int i = 0; i < 8; ++i) {
        const int flat = i * 1024 + t * 4;
        srow[i] = flat >> 7;
        scol[i] = flat & 127;
    }

    int T = blockIdx.x;
    float4 pf[8];
    if (T < n_tiles) {  // prefetch first tile
#pragma unroll
        for (int i = 0; i < 8; ++i) {
            int node = T * 64 + srow[i];
            if (node > n_nodes - 1) node = n_nodes - 1;  // clamp; never stored
            pf[i] = *(const float4*)(X + (size_t)node * EMBED + scol[i]);
        }
    }

    for (; T < n_tiles; T += gridDim.x) {
        const int mblk = T * 64;

#pragma unroll
        for (int i = 0; i < 8; ++i) {
            half4 h;
            h[0] = (_Float16)pf[i].x; h[1] = (_Float16)pf[i].y;
            h[2] = (_Float16)pf[i].z; h[3] = (_Float16)pf[i].w;
            *(half4*)(xs + srow[i] * 136 + scol[i]) = h;
        }
        __syncthreads();  // S1: stage visible

        const int Tn = T + gridDim.x;
        if (Tn < n_tiles) {
#pragma unroll
            for (int i = 0; i < 8; ++i) {
                int node = Tn * 64 + srow[i];
                if (node > n_nodes - 1) node = n_nodes - 1;
                pf[i] = *(const float4*)(X + (size_t)node * EMBED + scol[i]);
            }
        }

        floatx4 acc[4][4];
#pragma unroll
        for (int a = 0; a < 4; ++a)
#pragma unroll
            for (int b = 0; b < 4; ++b)
                acc[a][b] = (floatx4){0.f, 0.f, 0.f, 0.f};

#pragma unroll
        for (int ks = 0; ks < 4; ++ks) {
            const int k0 = ks * 32 + quad * 8;
            half8 xf[4];
#pragma unroll
            for (int mf = 0; mf < 4; ++mf)
                xf[mf] = *(const half8*)(xs + (mf * 16 + lm) * 136 + k0);
#pragma unroll
            for (int jf = 0; jf < 4; ++jf) {
                const int j = w * 64 + jf * 16 + lm;
                const half8 wf = *(const half8*)(WT + (size_t)j * EMBED + k0);
#pragma unroll
                for (int mf = 0; mf < 4; ++mf)
                    acc[mf][jf] = __builtin_amdgcn_mfma_f32_16x16x32_f16(wf, xf[mf], acc[mf][jf], 0, 0, 0);
            }
        }
        __syncthreads();  // S2

#pragma unroll
        for (int mf = 0; mf < 4; ++mf) {
#pragma unroll
            for (int jf = 0; jf < 4; ++jf) {
                half4 h;
#pragma unroll
                for (int r = 0; r < 4; ++r) h[r] = (_Float16)acc[mf][jf][r];
                *(half4*)(outs + (mf * 16 + lm) * 264 + w * 64 + jf * 16 + quad * 4) = h;
            }
        }
        __syncthreads();  // S3

#pragma unroll
        for (int i = 0; i < 8; ++i) {
            const int idx8 = i * 256 + t;
            const int node = idx8 >> 5, jj = idx8 & 31;
            if (mblk + node < n_nodes)
                *(half8*)(AB + (size_t)(mblk + node) * 256 + jj * 8) =
                    *(const half8*)(outs + node * 264 + jj * 8);
        }
        __syncthreads();  // S4
    }
}

// --- Kernel 2: per-edge MLP over SORTED edges — PLAIN HIP (no asm).
// 16 edges/group; each wave owns a contiguous span of NPW groups (sorted
// row-runs => the wave coalescer merges duplicate-row A-gathers into one
// 64B line request before they consume request slots). Two groups per
// iteration for ILP; stores route via original edge id (sE).
#define NPW 16
__global__ __launch_bounds__(256, 3) void edge_mlp(
    const _Float16* __restrict__ AB, const int* __restrict__ sR,
    const int* __restrict__ sC, const int* __restrict__ sE,
    const _Float16* __restrict__ b1f, const _Float16* __restrict__ W2PT,
    const float* __restrict__ b2, float* __restrict__ out, int n_edges) {
    const int lane = threadIdx.x & 63, lm = lane & 15, quad = lane >> 4;
    const int G = (n_edges + 15) / 16;         // 16-edge groups
    const int wid = blockIdx.x * 4 + (threadIdx.x >> 6);
    const int base = wid * NPW;
    if (base >= G) return;

    const float b2v = b2[lm & 1];  // only meaningful when lm<2

    half8 wv[4], bvv[4];
#pragma unroll
    for (int ks = 0; ks < 4; ++ks) {
        wv[ks]  = *(const half8*)(W2PT + lm * 128 + ks * 32 + quad * 8);
        bvv[ks] = *(const half8*)(b1f + ks * 32 + quad * 8);
    }

    auto cg = [&](int g) { return g < G ? g : G - 1; };

    // Prefetched indices for the current pair of groups.
    int r0 = sR[cg(base) * 16 + lm],     c0 = sC[cg(base) * 16 + lm];
    int r1 = sR[cg(base + 1) * 16 + lm], c1 = sC[cg(base + 1) * 16 + lm];

    for (int k = 0; k < NPW; k += 2) {
        const int g0 = cg(base + k), g1 = cg(base + k + 1);

        // Issue all 16 gathers (both groups) + eids; compiler schedules.
        const _Float16* a0p = AB + (size_t)(unsigned)r0 * 256 + quad * 8;
        const _Float16* b0p = AB + (size_t)(unsigned)c0 * 256 + 128 + quad * 8;
        const _Float16* a1p = AB + (size_t)(unsigned)r1 * 256 + quad * 8;
        const _Float16* b1p = AB + (size_t)(unsigned)c1 * 256 + 128 + quad * 8;
        half8 d0[8], d1[8];
#pragma unroll
        for (int ks = 0; ks < 4; ++ks) {
            d0[ks]     = *(const half8*)(a0p + ks * 32);
            d0[ks + 4] = *(const half8*)(b0p + ks * 32);
            d1[ks]     = *(const half8*)(a1p + ks * 32);
            d1[ks + 4] = *(const half8*)(b1p + ks * 32);
        }
        const intx4 e0 = *(const intx4*)(sE + g0 * 16 + quad * 4);
        const intx4 e1 = *(const intx4*)(sE + g1 * 16 + quad * 4);

        // Prefetch next pair's indices (sequential stream; harmless at tail).
        const int gn0 = cg(base + k + 2), gn1 = cg(base + k + 3);
        r0 = sR[gn0 * 16 + lm]; c0 = sC[gn0 * 16 + lm];
        r1 = sR[gn1 * 16 + lm]; c1 = sC[gn1 * 16 + lm];

        floatx4 acc0 = (floatx4){0.f, 0.f, 0.f, 0.f};
        floatx4 acc1 = (floatx4){0.f, 0.f, 0.f, 0.f};
#pragma unroll
        for (int ks = 0; ks < 4; ++ks) {
            half8 h0 = d0[ks] + d0[ks + 4] + bvv[ks];
            half8 h1 = d1[ks] + d1[ks + 4] + bvv[ks];
#pragma unroll
            for (int j = 0; j < 8; ++j) {
                h0[j] = h0[j] > (_Float16)0.f ? h0[j] : (_Float16)0.f;
                h1[j] = h1[j] > (_Float16)0.f ? h1[j] : (_Float16)0.f;
            }
            acc0 = __builtin_amdgcn_mfma_f32_16x16x32_f16(h0, wv[ks], acc0, 0, 0, 0);
            acc1 = __builtin_amdgcn_mfma_f32_16x16x32_f16(h1, wv[ks], acc1, 0, 0, 0);
        }

        // D[m=quad*4+r][n=lm]: edge = group*16 + quad*4 + r, class = lm.
        if (lm < 2) {
#pragma unroll
            for (int r = 0; r < 4; ++r) {
                const int i0 = r == 0 ? e0[0] : r == 1 ? e0[1] : r == 2 ? e0[2] : e0[3];
                const int i1 = r == 0 ? e1[0] : r == 1 ? e1[1] : r == 2 ? e1[2] : e1[3];
                out[(size_t)(unsigned)i0 * 2 + lm] = acc0[r] + b2v;
                out[(size_t)(unsigned)i1 * 2 + lm] = acc1[r] + b2v;
            }
        }
    }
}

extern "C" void kernel_launch(void* const* d_in, const int* in_sizes, int n_in,
                              void* d_out, int out_size, void* d_ws, size_t ws_size,
                              hipStream_t stream) {
    const float* X   = (const float*)d_in[0];
    const int*   idx = (const int*)d_in[1];
    const float* W1  = (const float*)d_in[2];
    const float* b1  = (const float*)d_in[3];
    const float* W2  = (const float*)d_in[4];
    const float* b2  = (const float*)d_in[5];
    float* out = (float*)d_out;

    const int n_nodes = in_sizes[0] / EMBED;   // 100000
    const int n_edges = in_sizes[1] / 2;       // 500000

    const int NB  = (n_nodes + 1023) / 1024;   // 98 scan blocks (<=128)
    const int G   = (n_edges + 15) / 16;       // 31250 groups
    const int G16 = G * 16;

    // ws carve (256B aligned): flag | AB | WT | W2PT+b1f | cnt | bsum | sR/sC/sE
    char* ws = (char*)d_ws;
    int*      flag = (int*)ws;
    _Float16* AB   = (_Float16*)(ws + 256);
    _Float16* WT   = (_Float16*)(ws + 256 + (size_t)n_nodes * 512);
    _Float16* W2PT = WT + 256 * 128;
    _Float16* b1f  = W2PT + 16 * 128;
    char* p = (char*)(b1f + 128);
    p = (char*)(((uintptr_t)p + 255) & ~(uintptr_t)255);
    int*   cnt  = (int*)p;              p += (size_t)NB * 1024 * 4;
    int*   bsum = (int*)p;              p += 1024;
    int*   sR   = (int*)p;              p += (size_t)G16 * 4;
    int*   sC   = (int*)p;              p += (size_t)G16 * 4;
    int*   sE   = (int*)p;              p += (size_t)G16 * 4;

    const int n_tiles = (n_nodes + 63) / 64;   // 1563

    prep<<<129 + NB, 256, 0, stream>>>(W1, W2, b1, idx, WT, W2PT, b1f, flag, cnt);
    gemm_ab<<<782, 256, 0, stream>>>(X, WT, AB, n_nodes, n_tiles);
    hist<<<256, 256, 0, stream>>>(idx, flag, cnt, n_edges);
    scan1<<<NB, 1024, 0, stream>>>(cnt, bsum, n_nodes);
    scan2<<<1, 128, 0, stream>>>(bsum, NB, sR, sC, sE, n_edges, G16);
    scatter<<<256, 256, 0, stream>>>(idx, flag, cnt, bsum, sR, sC, sE, n_edges);
    // Each wave: contiguous NPW-group span (sorted adjacency -> coalescing).
    const int nblk = (G + 4 * NPW - 1) / (4 * NPW);   // 489
    edge_mlp<<<nblk, 256, 0, stream>>>(
        AB, sR, sC, sE, b1f, W2PT, b2, out, n_edges);
}

// Round 9
// 170.220 us; speedup vs baseline: 1.1400x; 1.1400x over previous
//
#include <hip/hip_runtime.h>
#include <hip/hip_bf16.h>

// EdgePredictor: out[e] = relu(concat(X[row], X[col]) @ W1 + b1) @ W2 + b2
// Precompute per-node AB[n][256] = {X[n]@W1[:128,:] | X[n]@W1[128:,:]} in f16.
// Per edge: out = relu(A[row] + B[col] + b1) @ W2 + b2.
//
// R18 = R17 with a one-line-class correctness fix: R17's __shfl of the
// edge ids sat INSIDE `if (lm < 2)` — source lanes (lm=2..15) were
// inactive in that branch, so __shfl returned undefined data and stores
// went to garbage addresses (absmax 0.97). The shfls are now hoisted to
// wave-uniform scope; guards apply only to the store. The R17 experiment
// (8-bucket row-range partition -> XCD-affine consumption) is unchanged:
// theory is the 41.4us edge_mlp flatline = Infinity-Fabric service
// ceiling (6.2 TB/s, tier-invariant), attacked via XCD-local L2 reuse
// (per-bucket A-panel = 3.2MB < 4MiB XCD L2; bucket = blockIdx&7).

#define EMBED 128

typedef _Float16 half8 __attribute__((ext_vector_type(8)));
typedef _Float16 half4 __attribute__((ext_vector_type(4)));
typedef float floatx4 __attribute__((ext_vector_type(4)));
typedef int intx4 __attribute__((ext_vector_type(4)));

// --- Kernel 0: fused prep.
// Blocks 0..127: transpose+convert W1 (256x128 f32) -> WT (256x128 f16).
// Block 128: idx-mode ballot; W2PT[16][128]; b1f[128]; zero bcnt[8].
__global__ __launch_bounds__(256) void prep(
    const float* __restrict__ W1, const float* __restrict__ W2,
    const float* __restrict__ b1, const int* __restrict__ idx,
    _Float16* __restrict__ WT, _Float16* __restrict__ W2PT,
    _Float16* __restrict__ b1f, int* __restrict__ flag,
    int* __restrict__ bcnt) {
    if (blockIdx.x < 128) {
        __shared__ float lds[16][17];
        const int ty = threadIdx.x >> 4, tx = threadIdx.x & 15;
        const int r0 = (blockIdx.x >> 3) * 16;   // source W1 row tile
        const int c0 = (blockIdx.x & 7) * 16;    // source W1 col tile
        lds[ty][tx] = W1[(r0 + ty) * 128 + c0 + tx];
        __syncthreads();
        const int jbase = c0 + (r0 >= 128 ? 128 : 0);
        const int kbase = r0 & 127;
        WT[(size_t)(jbase + ty) * 128 + kbase + tx] = (_Float16)lds[tx][ty];
    } else {
        const int t = threadIdx.x;
        if (t < 64) {  // int64 layout iff first 64 high words are all zero
            const int hw = idx[2 * t + 1];
            const unsigned long long m = __ballot(hw != 0);
            if (t == 0) *flag = (m == 0ull) ? 1 : 0;
        }
        if (t < 8) bcnt[t] = 0;
        if (t < 128) b1f[t] = (_Float16)b1[t];
        for (int i = t; i < 2048; i += 256) {  // W2PT[n][k] = n<2 ? W2[k][n] : 0
            const int n = i >> 7, k = i & 127;
            W2PT[i] = (n < 2) ? (_Float16)W2[k * 2 + n] : (_Float16)0.f;
        }
    }
}

// --- Kernel P: 8-way partition by row range. Per grid-stride chunk:
// LDS-count buckets, reserve global runs (1 atomicAdd per bucket per
// block), write 16B (r,c,e,0) records into the reserved slots.
__global__ __launch_bounds__(256) void partition(
    const int* __restrict__ eidx, const int* __restrict__ flag,
    int* __restrict__ bcnt, int* __restrict__ recs, int cap,
    int n_edges, int n_nodes) {
    __shared__ int lcnt[8], lbase[8];
    const int t = threadIdx.x;
    const int mode = *flag;
    const unsigned bsize = (unsigned)(n_nodes + 7) / 8u;
    for (int base = blockIdx.x * 256; base < n_edges; base += gridDim.x * 256) {
        const int e = base + t;
        int r = 0, c = 0, b = 0;
        const bool act = e < n_edges;
        if (act) {
            r = eidx[(size_t)e << mode];
            c = eidx[((size_t)n_edges + e) << mode];
            b = (int)((unsigned)r / bsize);
        }
        if (t < 8) lcnt[t] = 0;
        __syncthreads();
        int myoff = 0;
        if (act) myoff = atomicAdd(&lcnt[b], 1);
        __syncthreads();
        if (t < 8) lbase[t] = atomicAdd(&bcnt[t], lcnt[t]);
        __syncthreads();
        if (act) {
            const size_t p = (size_t)b * cap + lbase[b] + myoff;
            *(intx4*)(recs + p * 4) = (intx4){r, c, e, 0};
        }
        __syncthreads();  // lcnt/lbase reuse next chunk
    }
}

// --- Kernel 1: AB = [X | X] @ Wcat via f16 MFMA, operand-swapped
// (A-operand = W-frag so D rows are output cols). Grid-stride, 2 tiles per
// block; next tile's X loads prefetched into registers during compute.
__global__ __launch_bounds__(256) void gemm_ab(
    const float* __restrict__ X, const _Float16* __restrict__ WT,
    _Float16* __restrict__ AB, int n_nodes, int n_tiles) {
    __shared__ _Float16 sh[64 * 264];  // 33792 B union: xs(17408) / outs(33792)
    _Float16* xs   = sh;               // stride 136
    _Float16* outs = sh;               // stride 264
    const int t = threadIdx.x;
    const int w = t >> 6, lane = t & 63, lm = lane & 15, quad = lane >> 4;

    int srow[8], scol[8];
#pragma unroll
    for (int i = 0; i < 8; ++i) {
        const int flat = i * 1024 + t * 4;
        srow[i] = flat >> 7;
        scol[i] = flat & 127;
    }

    int T = blockIdx.x;
    float4 pf[8];
    if (T < n_tiles) {  // prefetch first tile
#pragma unroll
        for (int i = 0; i < 8; ++i) {
            int node = T * 64 + srow[i];
            if (node > n_nodes - 1) node = n_nodes - 1;  // clamp; never stored
            pf[i] = *(const float4*)(X + (size_t)node * EMBED + scol[i]);
        }
    }

    for (; T < n_tiles; T += gridDim.x) {
        const int mblk = T * 64;

#pragma unroll
        for (int i = 0; i < 8; ++i) {
            half4 h;
            h[0] = (_Float16)pf[i].x; h[1] = (_Float16)pf[i].y;
            h[2] = (_Float16)pf[i].z; h[3] = (_Float16)pf[i].w;
            *(half4*)(xs + srow[i] * 136 + scol[i]) = h;
        }
        __syncthreads();  // S1: stage visible

        const int Tn = T + gridDim.x;
        if (Tn < n_tiles) {
#pragma unroll
            for (int i = 0; i < 8; ++i) {
                int node = Tn * 64 + srow[i];
                if (node > n_nodes - 1) node = n_nodes - 1;
                pf[i] = *(const float4*)(X + (size_t)node * EMBED + scol[i]);
            }
        }

        floatx4 acc[4][4];
#pragma unroll
        for (int a = 0; a < 4; ++a)
#pragma unroll
            for (int b = 0; b < 4; ++b)
                acc[a][b] = (floatx4){0.f, 0.f, 0.f, 0.f};

#pragma unroll
        for (int ks = 0; ks < 4; ++ks) {
            const int k0 = ks * 32 + quad * 8;
            half8 xf[4];
#pragma unroll
            for (int mf = 0; mf < 4; ++mf)
                xf[mf] = *(const half8*)(xs + (mf * 16 + lm) * 136 + k0);
#pragma unroll
            for (int jf = 0; jf < 4; ++jf) {
                const int j = w * 64 + jf * 16 + lm;
                const half8 wf = *(const half8*)(WT + (size_t)j * EMBED + k0);
#pragma unroll
                for (int mf = 0; mf < 4; ++mf)
                    acc[mf][jf] = __builtin_amdgcn_mfma_f32_16x16x32_f16(wf, xf[mf], acc[mf][jf], 0, 0, 0);
            }
        }
        __syncthreads();  // S2

#pragma unroll
        for (int mf = 0; mf < 4; ++mf) {
#pragma unroll
            for (int jf = 0; jf < 4; ++jf) {
                half4 h;
#pragma unroll
                for (int r = 0; r < 4; ++r) h[r] = (_Float16)acc[mf][jf][r];
                *(half4*)(outs + (mf * 16 + lm) * 264 + w * 64 + jf * 16 + quad * 4) = h;
            }
        }
        __syncthreads();  // S3

#pragma unroll
        for (int i = 0; i < 8; ++i) {
            const int idx8 = i * 256 + t;
            const int node = idx8 >> 5, jj = idx8 & 31;
            if (mblk + node < n_nodes)
                *(half8*)(AB + (size_t)(mblk + node) * 256 + jj * 8) =
                    *(const half8*)(outs + node * 264 + jj * 8);
        }
        __syncthreads();  // S4
    }
}

// --- Kernel 2: per-edge MLP over bucketed records — PLAIN HIP.
// bucket = blockIdx&7 (round-robin XCD dispatch -> bucket's 3.2MB A-panel
// becomes XCD-L2-resident). 16 edges/group; 2 groups/iter for ILP; record
// stream per group is 256B contiguous; stores via original edge id.
// R18 fix: eid __shfl at wave-uniform scope (all 64 lanes active).
__global__ __launch_bounds__(256, 3) void edge_mlp(
    const _Float16* __restrict__ AB, const int* __restrict__ recs,
    const int* __restrict__ bcnt, int cap,
    const _Float16* __restrict__ b1f, const _Float16* __restrict__ W2PT,
    const float* __restrict__ b2, float* __restrict__ out) {
    const int lane = threadIdx.x & 63, lm = lane & 15, quad = lane >> 4;
    const int bkt = blockIdx.x & 7;
    const int wslot = (blockIdx.x >> 3) * 4 + (threadIdx.x >> 6);
    const int WPB = (gridDim.x >> 3) * 4;     // waves per bucket
    const int cnt = bcnt[bkt];
    if (cnt == 0) return;
    const int G = (cnt + 15) >> 4;            // 16-edge groups in bucket
    const int* rb = recs + (size_t)bkt * cap * 4;

    const float b2v = b2[lm & 1];  // only meaningful when lm<2

    half8 wv[4], bvv[4];
#pragma unroll
    for (int ks = 0; ks < 4; ++ks) {
        wv[ks]  = *(const half8*)(W2PT + lm * 128 + ks * 32 + quad * 8);
        bvv[ks] = *(const half8*)(b1f + ks * 32 + quad * 8);
    }

    for (int g0 = 2 * wslot; g0 < G; g0 += 2 * WPB) {
        const int g1 = g0 + 1;
        int p0 = g0 * 16 + lm; p0 = p0 < cnt ? p0 : cnt - 1;
        int p1 = g1 * 16 + lm; p1 = p1 < cnt ? p1 : cnt - 1;
        const intx4 rec0 = *(const intx4*)(rb + (size_t)p0 * 4);
        const intx4 rec1 = *(const intx4*)(rb + (size_t)p1 * 4);

        // Gathers for both groups (compiler schedules; 12 waves/CU TLP).
        const _Float16* a0p = AB + (size_t)(unsigned)rec0[0] * 256 + quad * 8;
        const _Float16* b0p = AB + (size_t)(unsigned)rec0[1] * 256 + 128 + quad * 8;
        const _Float16* a1p = AB + (size_t)(unsigned)rec1[0] * 256 + quad * 8;
        const _Float16* b1p = AB + (size_t)(unsigned)rec1[1] * 256 + 128 + quad * 8;
        half8 d0[8], d1[8];
#pragma unroll
        for (int ks = 0; ks < 4; ++ks) {
            d0[ks]     = *(const half8*)(a0p + ks * 32);
            d0[ks + 4] = *(const half8*)(b0p + ks * 32);
            d1[ks]     = *(const half8*)(a1p + ks * 32);
            d1[ks + 4] = *(const half8*)(b1p + ks * 32);
        }

        floatx4 acc0 = (floatx4){0.f, 0.f, 0.f, 0.f};
        floatx4 acc1 = (floatx4){0.f, 0.f, 0.f, 0.f};
#pragma unroll
        for (int ks = 0; ks < 4; ++ks) {
            half8 h0 = d0[ks] + d0[ks + 4] + bvv[ks];
            half8 h1 = d1[ks] + d1[ks + 4] + bvv[ks];
#pragma unroll
            for (int j = 0; j < 8; ++j) {
                h0[j] = h0[j] > (_Float16)0.f ? h0[j] : (_Float16)0.f;
                h1[j] = h1[j] > (_Float16)0.f ? h1[j] : (_Float16)0.f;
            }
            acc0 = __builtin_amdgcn_mfma_f32_16x16x32_f16(h0, wv[ks], acc0, 0, 0, 0);
            acc1 = __builtin_amdgcn_mfma_f32_16x16x32_f16(h1, wv[ks], acc1, 0, 0, 0);
        }

        // D[m=quad*4+r][n=lm]: edge m's eid lives in lane (quad*4+r)'s
        // rec[2]. __shfl MUST run at wave-uniform scope (R17 bug: it sat
        // inside `if (lm<2)` where source lanes 2..15 were inactive).
        const int ez0 = rec0[2], ez1 = rec1[2];
#pragma unroll
        for (int r = 0; r < 4; ++r) {
            const int src = quad * 4 + r;          // lane src has lm == src
            const int i0 = __shfl(ez0, src, 64);   // all 64 lanes active
            const int i1 = __shfl(ez1, src, 64);
            if (lm < 2) {
                if (g0 * 16 + src < cnt)
                    out[(size_t)(unsigned)i0 * 2 + lm] = acc0[r] + b2v;
                if (g1 * 16 + src < cnt)
                    out[(size_t)(unsigned)i1 * 2 + lm] = acc1[r] + b2v;
            }
        }
    }
}

extern "C" void kernel_launch(void* const* d_in, const int* in_sizes, int n_in,
                              void* d_out, int out_size, void* d_ws, size_t ws_size,
                              hipStream_t stream) {
    const float* X   = (const float*)d_in[0];
    const int*   idx = (const int*)d_in[1];
    const float* W1  = (const float*)d_in[2];
    const float* b1  = (const float*)d_in[3];
    const float* W2  = (const float*)d_in[4];
    const float* b2  = (const float*)d_in[5];
    float* out = (float*)d_out;

    const int n_nodes = in_sizes[0] / EMBED;   // 100000
    const int n_edges = in_sizes[1] / 2;       // 500000
    const int cap = n_edges;                   // per-bucket record capacity

    // ws carve (256B aligned): flag+bcnt | AB | WT | W2PT | b1f | recs
    char* ws = (char*)d_ws;
    int*      flag = (int*)ws;
    int*      bcnt = (int*)(ws + 64);
    _Float16* AB   = (_Float16*)(ws + 256);
    _Float16* WT   = (_Float16*)(ws + 256 + (size_t)n_nodes * 512);
    _Float16* W2PT = WT + 256 * 128;
    _Float16* b1f  = W2PT + 16 * 128;
    char* p = (char*)(b1f + 128);
    p = (char*)(((uintptr_t)p + 255) & ~(uintptr_t)255);
    int* recs = (int*)p;   // 8 * cap * 16 B = 32 MB

    const int n_tiles = (n_nodes + 63) / 64;   // 1563

    prep<<<129, 256, 0, stream>>>(W1, W2, b1, idx, WT, W2PT, b1f, flag, bcnt);
    partition<<<256, 256, 0, stream>>>(idx, flag, bcnt, recs, cap,
                                       n_edges, n_nodes);
    gemm_ab<<<782, 256, 0, stream>>>(X, WT, AB, n_nodes, n_tiles);
    // 768 blocks: blockIdx&7 = bucket = XCD (round-robin dispatch);
    // 96 blocks x 4 waves per bucket; ~10 group-pairs per wave.
    edge_mlp<<<768, 256, 0, stream>>>(
        AB, recs, bcnt, cap, b1f, W2PT, b2, out);
}

// Round 10
// 145.920 us; speedup vs baseline: 1.3299x; 1.1665x over previous
//
#include <hip/hip_runtime.h>
#include <hip/hip_bf16.h>

// EdgePredictor: out[e] = relu(concat(X[row], X[col]) @ W1 + b1) @ W2 + b2
// Precompute per-node AB[n][256] = {X[n]@W1[:128,:] | X[n]@W1[128:,:]} in f16.
// Per edge: out = relu(A[row] + B[col] + b1) @ W2 + b2.
//
// R19: edge_mlp is at its practical roofline — 40.5-41.4us across FIVE
// structural variables (concurrency R11-R14, cache tier R12, sorted
// coalescing R16, occupancy 22-36%, XCD-L2 affinity R18: FETCH 118->96MB
// with dur UNCHANGED). 6.2 TB/s effective == chip streaming ceiling for
// this scatter pattern; sort+dedup residue (~-14us) costs >=13us of
// preprocessing (measured). Revert to R14 (best, 144.9) and spend the
// round on the last theorized lever: gemm_ab re-reads each wave's 16KB
// WT j-slice from L2 EVERY tile (64KB/block > 32KB L1 -> thrash; ~100MB
// of its ~200MB vector-memory volume). WT frags are tile-invariant per
// lane -> hoist 16 half8 (64 VGPR) into registers before the tile loop.
// launch_bounds(256,2) for the ~200-VGPR budget (8 waves/CU).

#define EMBED 128

typedef _Float16 half8 __attribute__((ext_vector_type(8)));
typedef _Float16 half4 __attribute__((ext_vector_type(4)));
typedef float floatx4 __attribute__((ext_vector_type(4)));

// --- Kernel 0: fused prep.
// Blocks 0..127: transpose+convert W1 (256x128 f32) -> WT (256x128 f16),
//   WT[j][k] = Wcat[k][j] (Wcat = [W1 top | W1 bottom] per concat split).
// Block 128: idx-mode ballot detect; W2PT[16][128] f16; b1f[128] f16.
__global__ __launch_bounds__(256) void prep(
    const float* __restrict__ W1, const float* __restrict__ W2,
    const float* __restrict__ b1, const int* __restrict__ idx,
    _Float16* __restrict__ WT, _Float16* __restrict__ W2PT,
    _Float16* __restrict__ b1f, int* __restrict__ flag) {
    if (blockIdx.x < 128) {
        __shared__ float lds[16][17];
        const int ty = threadIdx.x >> 4, tx = threadIdx.x & 15;
        const int r0 = (blockIdx.x >> 3) * 16;   // source W1 row tile
        const int c0 = (blockIdx.x & 7) * 16;    // source W1 col tile
        lds[ty][tx] = W1[(r0 + ty) * 128 + c0 + tx];
        __syncthreads();
        const int jbase = c0 + (r0 >= 128 ? 128 : 0);
        const int kbase = r0 & 127;
        WT[(size_t)(jbase + ty) * 128 + kbase + tx] = (_Float16)lds[tx][ty];
    } else {
        const int t = threadIdx.x;
        if (t < 64) {  // int64 layout iff first 64 high words are all zero
            const int hw = idx[2 * t + 1];
            const unsigned long long m = __ballot(hw != 0);
            if (t == 0) *flag = (m == 0ull) ? 1 : 0;
        }
        if (t < 128) b1f[t] = (_Float16)b1[t];
        for (int i = t; i < 2048; i += 256) {  // W2PT[n][k] = n<2 ? W2[k][n] : 0
            const int n = i >> 7, k = i & 127;
            W2PT[i] = (n < 2) ? (_Float16)W2[k * 2 + n] : (_Float16)0.f;
        }
    }
}

// --- Kernel 1: AB = [X | X] @ Wcat via f16 MFMA, operand-swapped
// (A-operand = W-frag so D rows are output cols). Grid-stride, 2 tiles per
// block; next tile's X loads prefetched into registers during compute.
// R19: per-lane WT fragments hoisted to registers (tile-invariant) —
// eliminates the per-tile 64KB/block WT L2 re-read stream (~100MB total).
__global__ __launch_bounds__(256, 2) void gemm_ab(
    const float* __restrict__ X, const _Float16* __restrict__ WT,
    _Float16* __restrict__ AB, int n_nodes, int n_tiles) {
    __shared__ _Float16 sh[64 * 264];  // 33792 B union: xs(17408) / outs(33792)
    _Float16* xs   = sh;               // stride 136
    _Float16* outs = sh;               // stride 264
    const int t = threadIdx.x;
    const int w = t >> 6, lane = t & 63, lm = lane & 15, quad = lane >> 4;

    // Per-thread stage coordinates (fixed across tiles).
    int srow[8], scol[8];
#pragma unroll
    for (int i = 0; i < 8; ++i) {
        const int flat = i * 1024 + t * 4;
        srow[i] = flat >> 7;
        scol[i] = flat & 127;
    }

    // Hoisted WT fragments: wfr[jf][ks], tile-invariant per lane (64 VGPR).
    half8 wfr[4][4];
#pragma unroll
    for (int jf = 0; jf < 4; ++jf) {
        const int j = w * 64 + jf * 16 + lm;
#pragma unroll
        for (int ks = 0; ks < 4; ++ks)
            wfr[jf][ks] = *(const half8*)(WT + (size_t)j * EMBED + ks * 32 + quad * 8);
    }

    int T = blockIdx.x;
    float4 pf[8];
    if (T < n_tiles) {  // prefetch first tile
#pragma unroll
        for (int i = 0; i < 8; ++i) {
            int node = T * 64 + srow[i];
            if (node > n_nodes - 1) node = n_nodes - 1;  // clamp; never stored
            pf[i] = *(const float4*)(X + (size_t)node * EMBED + scol[i]);
        }
    }

    for (; T < n_tiles; T += gridDim.x) {
        const int mblk = T * 64;

        // Stage: spill prefetched registers to LDS (convert f32->f16 once).
#pragma unroll
        for (int i = 0; i < 8; ++i) {
            half4 h;
            h[0] = (_Float16)pf[i].x; h[1] = (_Float16)pf[i].y;
            h[2] = (_Float16)pf[i].z; h[3] = (_Float16)pf[i].w;
            *(half4*)(xs + srow[i] * 136 + scol[i]) = h;
        }
        __syncthreads();  // S1: stage visible

        // Prefetch next tile NOW — loads overlap this tile's MFMA+epilogue.
        const int Tn = T + gridDim.x;
        if (Tn < n_tiles) {
#pragma unroll
            for (int i = 0; i < 8; ++i) {
                int node = Tn * 64 + srow[i];
                if (node > n_nodes - 1) node = n_nodes - 1;
                pf[i] = *(const float4*)(X + (size_t)node * EMBED + scol[i]);
            }
        }

        floatx4 acc[4][4];  // [mf: node tile][jf: col tile]
#pragma unroll
        for (int a = 0; a < 4; ++a)
#pragma unroll
            for (int b = 0; b < 4; ++b)
                acc[a][b] = (floatx4){0.f, 0.f, 0.f, 0.f};

#pragma unroll
        for (int ks = 0; ks < 4; ++ks) {
            const int k0 = ks * 32 + quad * 8;
            half8 xf[4];  // B-operand: B[k][n=lane&15] = Xf16[node mf*16+lm][k]
#pragma unroll
            for (int mf = 0; mf < 4; ++mf)
                xf[mf] = *(const half8*)(xs + (mf * 16 + lm) * 136 + k0);
#pragma unroll
            for (int jf = 0; jf < 4; ++jf) {
#pragma unroll
                for (int mf = 0; mf < 4; ++mf)
                    acc[mf][jf] = __builtin_amdgcn_mfma_f32_16x16x32_f16(wfr[jf][ks], xf[mf], acc[mf][jf], 0, 0, 0);
            }
        }
        __syncthreads();  // S2: xs reads done before outs overwrites union

        // Pack D into LDS out tile: node-major [local node][j], stride 264.
        // D: col(lane&15) = node within mf-tile, row(quad*4+r) = output col j.
#pragma unroll
        for (int mf = 0; mf < 4; ++mf) {
#pragma unroll
            for (int jf = 0; jf < 4; ++jf) {
                half4 h;
#pragma unroll
                for (int r = 0; r < 4; ++r) h[r] = (_Float16)acc[mf][jf][r];
                *(half4*)(outs + (mf * 16 + lm) * 264 + w * 64 + jf * 16 + quad * 4) = h;
            }
        }
        __syncthreads();  // S3: outs visible

        // Coalesced store: 64 nodes x 512 B contiguous in AB (node-major).
#pragma unroll
        for (int i = 0; i < 8; ++i) {
            const int idx8 = i * 256 + t;         // half8 index in 64x256 tile
            const int node = idx8 >> 5, jj = idx8 & 31;
            if (mblk + node < n_nodes)
                *(half8*)(AB + (size_t)(mblk + node) * 256 + jj * 8) =
                    *(const half8*)(outs + node * 264 + jj * 8);
        }
        __syncthreads();  // S4: outs reads done before next tile's stage
    }
}

// Hand-counted waits; sched_barrier(0) after each (rule #18).
#define WAITVM(N)                                              \
    do {                                                       \
        asm volatile("s_waitcnt vmcnt(" #N ")" ::: "memory");  \
        __builtin_amdgcn_sched_barrier(0);                     \
    } while (0)

// --- Kernel 2: per-edge MLP (R14 verbatim — measured 144.9us total,
// passed). 16 edges/group, persistent waves, 2-deep asm ping-pong.
__global__ __launch_bounds__(256, 3) void edge_mlp(
    const _Float16* __restrict__ AB, const int* __restrict__ eidx,
    const int* __restrict__ flag, const _Float16* __restrict__ b1f,
    const _Float16* __restrict__ W2PT, const float* __restrict__ b2,
    float* __restrict__ out, float* __restrict__ dump, int n_edges) {
    const int lane = threadIdx.x & 63, lm = lane & 15, quad = lane >> 4;
    const int W = gridDim.x * 4;               // total waves
    const int G = (n_edges + 15) / 16;         // 16-edge groups
    const int wid = blockIdx.x * 4 + (threadIdx.x >> 6);
    if (wid >= G) return;

    const int mode = *flag;        // wave-uniform: 1 => int64-layout indices
    const float b2v = b2[lm & 1];  // only meaningful when lm<2
    const uint64_t dadr = (uint64_t)(dump + wid);
    const uint64_t qbyte = (uint64_t)(quad * 16);  // byte offset within row

    // Loop-invariant operands in registers.
    half8 wv[4], bv[4];
#pragma unroll
    for (int ks = 0; ks < 4; ++ks) {
        wv[ks] = *(const half8*)(W2PT + lm * 128 + ks * 32 + quad * 8);
        bv[ks] = *(const half8*)(b1f + ks * 32 + quad * 8);
    }
#pragma unroll
    for (int ks = 0; ks < 4; ++ks)
        asm volatile("" :: "v"(wv[ks]), "v"(bv[ks]));
    asm volatile("" :: "v"(b2v));

    auto idx_addr = [&](int g, int which) -> uint64_t {
        int e = g * 16 + lm;
        e = e < n_edges ? e : n_edges - 1;
        const size_t off = which ? ((size_t)n_edges + e) : (size_t)e;
        return (uint64_t)(eidx + (off << mode));
    };

    auto gissue = [&](int r, int c, half8* d) {
        const uint64_t ap = (uint64_t)(AB + ((size_t)(unsigned)r << 8)) + qbyte;
        const uint64_t bp = (uint64_t)(AB + ((size_t)(unsigned)c << 8) + 128) + qbyte;
        asm volatile("global_load_dwordx4 %0, %1, off"            : "=v"(d[0]) : "v"(ap));
        asm volatile("global_load_dwordx4 %0, %1, off offset:64"  : "=v"(d[1]) : "v"(ap));
        asm volatile("global_load_dwordx4 %0, %1, off offset:128" : "=v"(d[2]) : "v"(ap));
        asm volatile("global_load_dwordx4 %0, %1, off offset:192" : "=v"(d[3]) : "v"(ap));
        asm volatile("global_load_dwordx4 %0, %1, off"            : "=v"(d[4]) : "v"(bp));
        asm volatile("global_load_dwordx4 %0, %1, off offset:64"  : "=v"(d[5]) : "v"(bp));
        asm volatile("global_load_dwordx4 %0, %1, off offset:128" : "=v"(d[6]) : "v"(bp));
        asm volatile("global_load_dwordx4 %0, %1, off offset:192" : "=v"(d[7]) : "v"(bp));
    };

    auto comp = [&](int g, const half8* d) {
        floatx4 acc = (floatx4){0.f, 0.f, 0.f, 0.f};
#pragma unroll
        for (int ks = 0; ks < 4; ++ks) {
            half8 h = d[ks] + d[ks + 4] + bv[ks];
#pragma unroll
            for (int j = 0; j < 8; ++j)
                h[j] = h[j] > (_Float16)0.f ? h[j] : (_Float16)0.f;
            acc = __builtin_amdgcn_mfma_f32_16x16x32_f16(h, wv[ks], acc, 0, 0, 0);
        }
        const int eb = g * 16;
#pragma unroll
        for (int r = 0; r < 4; ++r) {
            const int ed = eb + quad * 4 + r;
            const bool real = (lm < 2) & (ed < n_edges);
            const uint64_t sa = real ? (uint64_t)(out + (size_t)ed * 2 + lm) : dadr;
            const float v = acc[r] + b2v;
            asm volatile("global_store_dword %0, %1, off" :: "v"(sa), "v"(v));
        }
    };

    // ---- prologue: enter the loop in steady-state queue shape ----
    int g0 = wid, g1 = wid + W;
    int r0i, c0i, r1i, c1i;
    {
        uint64_t a;
        a = idx_addr(g0, 0); asm volatile("global_load_dword %0, %1, off" : "=v"(r0i) : "v"(a));
        a = idx_addr(g0, 1); asm volatile("global_load_dword %0, %1, off" : "=v"(c0i) : "v"(a));
        a = idx_addr(g1, 0); asm volatile("global_load_dword %0, %1, off" : "=v"(r1i) : "v"(a));
        a = idx_addr(g1, 1); asm volatile("global_load_dword %0, %1, off" : "=v"(c1i) : "v"(a));
    }
    WAITVM(2);                         // idx(g0) done (idx(g1) may remain)
    half8 a0[8], a1[8];
    gissue(r0i, c0i, a0);              // 8 outstanding for g0
    {                                  // 4 dummy stores: match steady S(4)
        const float z = 0.f;
        asm volatile("global_store_dword %0, %1, off" :: "v"(dadr), "v"(z));
        asm volatile("global_store_dword %0, %1, off" :: "v"(dadr), "v"(z));
        asm volatile("global_store_dword %0, %1, off" :: "v"(dadr), "v"(z));
        asm volatile("global_store_dword %0, %1, off" :: "v"(dadr), "v"(z));
    }

    // ---- steady state: 2 phases/iter; waits vmcnt(12)/vmcnt(14) ----
    const int n = (G - wid + W - 1) / W;   // real groups for this wave (>=1)
    const int nloop = (n + 1) >> 1;        // odd n => one harmless dummy phase
    for (int it = 0; it < nloop; ++it) {
        // Phase A: comp(g0,a0); gather(g1)->a1; idx(g0+2W)->r0i,c0i.
        {
            const int g2 = g1 + W;
            WAITVM(12);                          // idx(g1) ready
            uint64_t a;
            a = idx_addr(g2, 0); asm volatile("global_load_dword %0, %1, off" : "=v"(r0i) : "v"(a));
            a = idx_addr(g2, 1); asm volatile("global_load_dword %0, %1, off" : "=v"(c0i) : "v"(a));
            gissue(r1i, c1i, a1);
            WAITVM(14);                          // a0 ready
            comp(g0, a0);
        }
        // Phase B: comp(g1,a1); gather(g2)->a0; idx(g1+2W)->r1i,c1i.
        {
            const int g2 = g1 + W, g3 = g2 + W;
            WAITVM(12);                          // idx(g2) ready
            uint64_t a;
            a = idx_addr(g3, 0); asm volatile("global_load_dword %0, %1, off" : "=v"(r1i) : "v"(a));
            a = idx_addr(g3, 1); asm volatile("global_load_dword %0, %1, off" : "=v"(c1i) : "v"(a));
            gissue(r0i, c0i, a0);
            WAITVM(14);                          // a1 ready
            comp(g1, a1);
        }
        g0 += 2 * W;
        g1 += 2 * W;
    }
}

extern "C" void kernel_launch(void* const* d_in, const int* in_sizes, int n_in,
                              void* d_out, int out_size, void* d_ws, size_t ws_size,
                              hipStream_t stream) {
    const float* X   = (const float*)d_in[0];
    const int*   idx = (const int*)d_in[1];
    const float* W1  = (const float*)d_in[2];
    const float* b1  = (const float*)d_in[3];
    const float* W2  = (const float*)d_in[4];
    const float* b2  = (const float*)d_in[5];
    float* out = (float*)d_out;

    const int n_nodes = in_sizes[0] / EMBED;   // 100000
    const int n_edges = in_sizes[1] / 2;       // 500000

    // ws: flag @0 | AB @256 (n_nodes*512 B) | WT 64KB | W2PT 4KB | b1f 256B
    //     | dump 3072 floats
    char* ws = (char*)d_ws;
    int*      flag = (int*)ws;
    _Float16* AB   = (_Float16*)(ws + 256);
    _Float16* WT   = (_Float16*)(ws + 256 + (size_t)n_nodes * 512);
    _Float16* W2PT = WT + 256 * 128;
    _Float16* b1f  = W2PT + 16 * 128;
    float*    dump = (float*)(b1f + 128);

    const int n_tiles = (n_nodes + 63) / 64;   // 1563

    prep<<<129, 256, 0, stream>>>(W1, W2, b1, idx, WT, W2PT, b1f, flag);
    gemm_ab<<<782, 256, 0, stream>>>(X, WT, AB, n_nodes, n_tiles);
    // 768 persistent blocks = 12 waves/CU; ~10 groups/wave.
    edge_mlp<<<768, 256, 0, stream>>>(
        AB, idx, flag, b1f, W2PT, b2, out, dump, n_edges);
}